// Round 8
// baseline (57.780 us; speedup 1.0000x reference)
//
#include <hip/hip_runtime.h>
#include <hip/hip_bf16.h>

typedef __attribute__((ext_vector_type(8))) short s16x8;
typedef __attribute__((ext_vector_type(4))) float f32x4;
typedef __attribute__((ext_vector_type(4))) float fl4;

__device__ __forceinline__ unsigned short f2bf(float f) {
  union { __hip_bfloat16 b; unsigned short u; } cv;
  cv.b = __float2bfloat16(f);
  return cv.u;
}

// HSTU fused, B=8 H=4 D=V=64 SEQ=1024.
// R8: max-TLP structure. 2048 blocks x 1 wave (2 waves/SIMD resident),
// NO LDS, NO barriers. All frags global->VGPR fp32 + in-reg cvt.
// Each wave owns 16 q-rows; swapped QK^T (verified R1/R3); PV slot map
// y(g,i) = 16*(i>>2) + 4g + (i&3) (+32 for pa1/vf1) (verified R1/R6).
__global__ __launch_bounds__(64, 4)
void hstu_fused(const float* __restrict__ tq, const float* __restrict__ tk,
                const float* __restrict__ tv, const int* __restrict__ ncand,
                float* __restrict__ out)
{
  const int bid = (int)blockIdx.x;
  const int bh  = bid & 31;                 // same bh -> same XCD (stride 32)
  const int jp  = bid >> 5;                 // 0..63
  const int rg  = (jp == 0) ? 0 : 64 - jp;  // heavy-first (rg0 = contextual rows)
  const int b = bh >> 2, h = bh & 3;
  const int l = (int)threadIdx.x;
  const int rl = l & 15, g = l >> 4;
  const int T = 1024 - ncand[b];
  const int qr = rg << 4;                   // wave's q-rows [qr, qr+16)
  const int rq = qr + rl;

  // ---- Q frags in-reg (alpha=1/8 folded): lane(rl,g) d in {8g..8g+7} u {32+8g..}
  s16x8 qf0, qf1;
  {
    const float* qs = tq + ((size_t)(b*1024 + rq))*256 + h*64;
    fl4 a  = *(const fl4*)(qs + g*8);
    fl4 b2 = *(const fl4*)(qs + g*8 + 4);
    fl4 c  = *(const fl4*)(qs + 32 + g*8);
    fl4 d2 = *(const fl4*)(qs + 36 + g*8);
#pragma unroll
    for (int j = 0; j < 4; ++j) {
      qf0[j]   = (short)f2bf(a[j]  * 0.125f);
      qf0[j+4] = (short)f2bf(b2[j] * 0.125f);
      qf1[j]   = (short)f2bf(c[j]  * 0.125f);
      qf1[j+4] = (short)f2bf(d2[j] * 0.125f);
    }
  }

  f32x4 zero = {0.f, 0.f, 0.f, 0.f};
  f32x4 oacc[4];
#pragma unroll
  for (int i = 0; i < 4; ++i) oacc[i] = zero;

  const int nkv = (rg == 0) ? 16 : (rg >> 2) + 1;   // causal tile bound

  for (int t = 0; t < nkv; ++t) {
    const float* kbase = tk + ((size_t)(b*1024 + t*64))*256 + h*64;
    const float* vbase = tv + ((size_t)(b*1024 + t*64))*256 + h*64;

    // ---- QK^T swapped: A = K frag (rows y = t4*16+rl, d-slots {8g..}u{32+8g..})
    f32x4 sacc[4];
#pragma unroll
    for (int i = 0; i < 4; ++i) sacc[i] = zero;
#pragma unroll
    for (int t4 = 0; t4 < 4; ++t4) {
      const float* kr = kbase + (size_t)(t4*16 + rl)*256;
      fl4 a  = *(const fl4*)(kr + g*8);
      fl4 b2 = *(const fl4*)(kr + g*8 + 4);
      fl4 c  = *(const fl4*)(kr + 32 + g*8);
      fl4 d2 = *(const fl4*)(kr + 36 + g*8);
      s16x8 kf0, kf1;
#pragma unroll
      for (int j = 0; j < 4; ++j) {
        kf0[j]   = (short)f2bf(a[j]);
        kf0[j+4] = (short)f2bf(b2[j]);
        kf1[j]   = (short)f2bf(c[j]);
        kf1[j+4] = (short)f2bf(d2[j]);
      }
      sacc[t4] = __builtin_amdgcn_mfma_f32_16x16x32_bf16(kf0, qf0, sacc[t4], 0, 0, 0);
      sacc[t4] = __builtin_amdgcn_mfma_f32_16x16x32_bf16(kf1, qf1, sacc[t4], 0, 0, 0);
    }

    // ---- silu + mask + pack P (slot (g,i): y = 16*(i>>2)+4g+(i&3), +32 for pa1)
    s16x8 pa0, pa1;
#pragma unroll
    for (int t4 = 0; t4 < 4; ++t4) {
#pragma unroll
      for (int r = 0; r < 4; ++r) {
        const int y = t*64 + t4*16 + 4*g + r;
        const float s = sacc[t4][r];
        const float sig = __builtin_amdgcn_rcpf(1.f + __expf(-s));
        const bool valid = (rq < 8) ? (y < T)
                         : ((y <= rq) && ((rq < T) || (y < T) || (y == rq)));
        const float a = valid ? s * sig : 0.f;
        const short bv = (short)f2bf(a);
        if (t4 < 2) pa0[(t4 & 1)*4 + r] = bv;
        else        pa1[(t4 & 1)*4 + r] = bv;
      }
    }

    // ---- PV: V frags direct from global columns (1/2048 folded)
    // vf0 slot i: V[16*(i>>2)+4g+(i&3)][vt*16+rl]; vf1: rows +32.
#pragma unroll
    for (int vt = 0; vt < 4; ++vt) {
      const float* vc = vbase + vt*16 + rl;
      s16x8 vf0, vf1;
#pragma unroll
      for (int j = 0; j < 4; ++j) {
        vf0[j]   = (short)f2bf(vc[(size_t)( 0 + 4*g + j)*256] * 4.8828125e-4f);
        vf0[j+4] = (short)f2bf(vc[(size_t)(16 + 4*g + j)*256] * 4.8828125e-4f);
        vf1[j]   = (short)f2bf(vc[(size_t)(32 + 4*g + j)*256] * 4.8828125e-4f);
        vf1[j+4] = (short)f2bf(vc[(size_t)(48 + 4*g + j)*256] * 4.8828125e-4f);
      }
      oacc[vt] = __builtin_amdgcn_mfma_f32_16x16x32_bf16(pa0, vf0, oacc[vt], 0, 0, 0);
      oacc[vt] = __builtin_amdgcn_mfma_f32_16x16x32_bf16(pa1, vf1, oacc[vt], 0, 0, 0);
    }
  }

  // ---- epilogue (verified R3): O[qr + 4g+r][vt*16+rl]
  float* dst = out + ((size_t)(b*1024 + qr))*256 + h*64;
#pragma unroll
  for (int vt = 0; vt < 4; ++vt)
#pragma unroll
    for (int r = 0; r < 4; ++r)
      dst[(size_t)(4*g + r)*256 + vt*16 + rl] = oacc[vt][r];
}

extern "C" void kernel_launch(void* const* d_in, const int* in_sizes, int n_in,
                              void* d_out, int out_size, void* d_ws, size_t ws_size,
                              hipStream_t stream) {
  (void)in_sizes; (void)n_in; (void)out_size; (void)d_ws; (void)ws_size;
  const float* tq = (const float*)d_in[0];
  const float* tk = (const float*)d_in[1];
  const float* tv = (const float*)d_in[2];
  const int*   nc = (const int*)d_in[4];
  float* out = (float*)d_out;
  hipLaunchKernelGGL(hstu_fused, dim3(2048), dim3(64), 0, stream, tq, tk, tv, nc, out);
}